// Round 18
// baseline (141.999 us; speedup 1.0000x reference)
//
#include <hip/hip_runtime.h>

#define B_   8
#define C_   64
#define W_   128
#define H_   128
#define K_   9
#define OUT_ 64
#define NPIX (B_*W_*H_)      // 131072
#define EPS_ 1e-5f

typedef __attribute__((ext_vector_type(8))) short bf16x8;
typedef __attribute__((ext_vector_type(4))) float f32x4;

// ---------------- workspace layout (float offsets) ----------------
#define FEATBF_OFF  0                      // B*W*H*C bf16 (4194304 f)
#define XPRE_OFF    4194304                // B*64*W*H bf16 (4194304 f)
#define OFFPRE_OFF  8388608                // B*9*W*H = 1179648
#define OFFH_OFF    9568256                // 4*B*9*W*H = 4718592 (c-split partials)
#define WT_OFF      14286848               // 9*64*64 bf16 (18432 f)
#define WP_OFF      14305280               // 64*81 = 5184
#define BNSTATS_OFF 14310464               // 18
#define GSTATS_OFF  14310500               // 256
#define STATS_BYTES ((18+18+256+256)*sizeof(float))

__device__ __forceinline__ unsigned pack2bf(float a, float b) {
    union { float f; unsigned u; } ua, ub;
    ua.f = a; ub.f = b;
    unsigned x = ua.u, y = ub.u;
    x += 0x7fffu + ((x >> 16) & 1u);       // RNE to bf16
    y += 0x7fffu + ((y >> 16) & 1u);
    return (x >> 16) | (y & 0xffff0000u);
}
__device__ __forceinline__ float bflo(unsigned u) {
    union { unsigned u; float f; } v; v.u = u << 16; return v.f;
}
__device__ __forceinline__ float bfhi(unsigned u) {
    union { unsigned u; float f; } v; v.u = u & 0xffff0000u; return v.f;
}

// ---------------- weight prep: w_dsc -> wTbf[k][o][c] bf16 ; w_off -> wP[c][dw][ck][dh] ----------------
__global__ void k_wprep(const float* __restrict__ w_dsc, unsigned short* __restrict__ wTbf,
                        const float* __restrict__ w_off, float* __restrict__ wP) {
    int bid = blockIdx.x;
    if (bid < 144) {
        int i = bid*256 + threadIdx.x;       // < 36864
        if (i >= 9*64*64) return;
        int c = i & 63;
        int o = (i >> 6) & 63;
        int k = i >> 12;
        union { float f; unsigned u; } v;
        v.f = w_dsc[(o*64 + c)*9 + k];
        unsigned x = v.u + 0x7fffu + ((v.u >> 16) & 1u);
        wTbf[i] = (unsigned short)(x >> 16);
    } else {
        int i = (bid-144)*256 + threadIdx.x; // < 5184
        if (i >= 64*81) return;
        int c    = i / 81;
        int rem  = i % 81;
        int dw   = rem / 27;
        int rem2 = rem % 27;
        int ck   = rem2 / 3;
        int dh   = rem2 % 3;
        wP[i] = w_off[ck*576 + c*9 + dw*3 + dh];
    }
}

// ---------------- merged: 3x3 conv (blocks 0..4095) + NCHW->NHWC bf16 (4096..5119) ----------------
// Conv: R13 form (best measured 45us; c-split x4, shuffle taps, scalar weights).
// fp32 path REQUIRED (discontinuous sampler, R7). b_off dropped (cancels in BN).
// nhwc is LDS-free (coalesced reads per c, 128B-chunk writes) and rides along in
// the same launch so its ~8us hides under the latency-bound conv.
__global__ __launch_bounds__(128) void k_conv_nhwc(const float* __restrict__ f,
                                                   const float* __restrict__ wP,
                                                   float* __restrict__ off_half,
                                                   unsigned short* __restrict__ featbf) {
    int t   = threadIdx.x;
    int bid = blockIdx.x;
    if (bid < 4096) {
        int b   = bid & 7;              // XCD swizzle
        int w   = (bid >> 3) & 127;
        int cq  = bid >> 10;            // c-quarter 0..3
        int h   = t;

        float em = (h == 0)   ? 0.f : 1.f;
        float ep = (h == 127) ? 0.f : 1.f;

        const float* fb = f + (size_t)b*1048576 + (size_t)(cq*16)*16384 + (size_t)w*128;
        const float* wb = wP + cq*16*81;

        float acc[9];
#pragma unroll
        for (int ck = 0; ck < 9; ck++) acc[ck] = 0.f;

#pragma unroll 4
        for (int c = 0; c < 16; c++) {
            const float* p  = fb + c*16384;
            const float* wc = wb + c*81;
#pragma unroll
            for (int dw = -1; dw <= 1; dw++) {
                int wy = w + dw;
                if ((unsigned)wy < 128u) {
                    const float* q = p + dw*128;
                    float v1 = q[h];
                    float v0 = __shfl_up(v1, 1);
                    float v2 = __shfl_down(v1, 1);
                    if (t == 64) v0 = q[63];
                    if (t == 63) v2 = q[64];
                    v0 *= em; v2 *= ep;
                    const float* ww = wc + (dw+1)*27;
#pragma unroll
                    for (int ck = 0; ck < 9; ck++)
                        acc[ck] += v0*ww[ck*3] + v1*ww[ck*3+1] + v2*ww[ck*3+2];
                }
            }
        }

        float* dst = off_half + (size_t)cq*1179648;
        int pixoff = (w << 7) + h;
#pragma unroll
        for (int ck = 0; ck < 9; ck++)
            dst[((b*9 + ck) << 14) + pixoff] = acc[ck];
    } else {
        int nb = bid - 4096;            // 0..1023
        int b  = nb & 7;                // XCD swizzle
        int w  = nb >> 3;
        int h  = t;
        const float* fp = f + (size_t)b*1048576 + (size_t)w*128 + h;
        unsigned short* obf = featbf + ((size_t)((b*128 + w)*128) + h)*64;
#pragma unroll 2
        for (int cc = 0; cc < 64; cc += 8) {
            float v0 = fp[(cc+0)*16384], v1 = fp[(cc+1)*16384];
            float v2 = fp[(cc+2)*16384], v3 = fp[(cc+3)*16384];
            float v4 = fp[(cc+4)*16384], v5 = fp[(cc+5)*16384];
            float v6 = fp[(cc+6)*16384], v7 = fp[(cc+7)*16384];
            uint4 u;
            u.x = pack2bf(v0, v1); u.y = pack2bf(v2, v3);
            u.z = pack2bf(v4, v5); u.w = pack2bf(v6, v7);
            *(uint4*)(obf + cc) = u;
        }
    }
}

// ---------------- sum quarters -> off_pre, BN stats ----------------
__global__ __launch_bounds__(256) void k_bn_stats(const float* __restrict__ off_half,
                                                  float* __restrict__ off_pre,
                                                  float* __restrict__ bnstats) {
    __shared__ float wred[4][2];
    int bid = blockIdx.x;           // 288 = b*36 + ck*4 + wq
    int b  = bid / 36;
    int rem = bid % 36;
    int ck = rem / 4;
    int wq = rem % 4;
    int t  = threadIdx.x;
    int base4 = (((b*9+ck) << 14) + wq*4096) >> 2;

    const float4* h0 = (const float4*)off_half;
    const float4* h1 = (const float4*)(off_half + 1179648);
    const float4* h2 = (const float4*)(off_half + 2359296);
    const float4* h3 = (const float4*)(off_half + 3538944);
    float4* op = (float4*)off_pre;

    float s = 0.f, q = 0.f;
#pragma unroll
    for (int i = 0; i < 4; i++) {
        int idx = base4 + t + i*256;
        float4 a = h0[idx], bb = h1[idx], cc = h2[idx], dd = h3[idx];
        float4 v;
        v.x = (a.x + bb.x) + (cc.x + dd.x);
        v.y = (a.y + bb.y) + (cc.y + dd.y);
        v.z = (a.z + bb.z) + (cc.z + dd.z);
        v.w = (a.w + bb.w) + (cc.w + dd.w);
        op[idx] = v;
        s += v.x + v.y + v.z + v.w;
        q += v.x*v.x + v.y*v.y + v.z*v.z + v.w*v.w;
    }
    for (int off = 32; off; off >>= 1) {
        s += __shfl_down(s, off);
        q += __shfl_down(q, off);
    }
    if ((t & 63) == 0) { wred[t >> 6][0] = s; wred[t >> 6][1] = q; }
    __syncthreads();
    if (t == 0) atomicAdd(&bnstats[ck*2],   wred[0][0]+wred[1][0]+wred[2][0]+wred[3][0]);
    if (t == 1) atomicAdd(&bnstats[ck*2+1], wred[0][1]+wred[1][1]+wred[2][1]+wred[3][1]);
}

// ---------------- fused: BN-finalize, offsets, 2-tap sample (bf16), MFMA, GN stats ----------------
// M-split x2: block = (b, w, h-half of 64 rows). R16 showed occupancy 20%
// (grid 1024, 4 blk/CU, barrier-idle waves); 2048 blocks at 18.9KB LDS -> 8/CU.
__global__ __launch_bounds__(256) void k_sample_dsc(const unsigned short* __restrict__ featbf,
                                                    const float* __restrict__ off_pre,
                                                    const float* __restrict__ bnstats,
                                                    const float* __restrict__ bn_gamma,
                                                    const float* __restrict__ bn_beta,
                                                    const unsigned short* __restrict__ wTbf,
                                                    const float* __restrict__ b_dsc,
                                                    unsigned short* __restrict__ xprebf,
                                                    float* __restrict__ gstats) {
    __shared__ __align__(16) unsigned char lds_samp[64*128]; // [h][c] bf16, XOR-swizzled rows
    __shared__ __align__(16) unsigned char lds_wk[64*128];   // [o][c] bf16, XOR-swizzled rows
    __shared__ float ynew[9][64];
    __shared__ float red[16][2];
    __shared__ float bnab[18];

    int t = threadIdx.x;
    int bid = blockIdx.x;              // 2048 = mh*1024 + w*8 + b
    int b = bid & 7, w = (bid >> 3) & 127, mh = bid >> 10;
    int hbase = mh * 64;

    // BN finalize (folded): per-block recompute, trivial
    if (t < 9) {
        float n    = (float)NPIX;
        float mean = bnstats[t*2] / n;
        float var  = bnstats[t*2+1] / n - mean*mean;
        float A    = bn_gamma[t] / sqrtf(var + EPS_);
        bnab[t*2]   = A;
        bnab[t*2+1] = bn_beta[t] - mean * A;
    }
    if (t < 16) { red[t][0] = 0.f; red[t][1] = 0.f; }
    __syncthreads();

    if (t < 64) {
        int h = hbase + t;
        float y[9];
#pragma unroll
        for (int ck = 0; ck < 9; ck++) {
            float v = off_pre[((b*9+ck) << 14) + (w << 7) + h];
            y[ck] = tanhf(bnab[ck*2]*v + bnab[ck*2+1]);
        }
        float ofn[9];
        ofn[4] = 0.f;
        ofn[5] = y[5]; ofn[6] = y[5]+y[6]; ofn[7] = y[5]+y[6]+y[7];
        ofn[3] = y[3]; ofn[2] = y[3]+y[2]; ofn[1] = y[3]+y[2]+y[1];
        ofn[0] = y[0]; ofn[8] = y[8];
#pragma unroll
        for (int k = 0; k < 9; k++) ynew[k][t] = (float)w + ofn[k];
    }

    f32x4 acc[4];
#pragma unroll
    for (int ni = 0; ni < 4; ni++) {
        acc[ni][0] = 0.f; acc[ni][1] = 0.f; acc[ni][2] = 0.f; acc[ni][3] = 0.f;
    }

    int lane = t & 63, wv = t >> 6;
    int m0 = wv * 16;                 // wave's local 16-row M tile
    int lm = lane & 15, lk = lane >> 4;
    int hsl = t >> 2;                 // local sampling row 0..63
    int cq  = t & 3;                  // quarter of the 128B row (16 ch)

    // prefetch k=0 weights into regs
    uint4 wv0, wv1;
    {
        const uint4* src = (const uint4*)wTbf;
        wv0 = src[t];
        wv1 = src[t + 256];
    }

    __syncthreads();

    for (int k = 0; k < 9; k++) {
        if (k) __syncthreads();       // previous iter's MFMA reads done

        // ---- write prefetched weight k-slice [64 o][64 c] bf16 into swizzled LDS ----
        {
#pragma unroll
            for (int i = 0; i < 2; i++) {
                int ci = t + i*256;                 // 0..511 16B chunks
                uint4 v = (i == 0) ? wv0 : wv1;
                int o  = ci >> 3;
                int cb = (ci & 7) << 4;
                *(uint4*)(lds_wk + o*128 + (cb ^ ((o & 7) << 4))) = v;
            }
        }

        // ---- 2-tap y-lerp sample, local row hsl (4 threads/row), 16 ch each ----
        // x_s is integer -> x-weights are {1,0} in-bounds, exact 0 outside
        {
            int hg = hbase + hsl;
            int x0 = k - 4 + hg;
            unsigned char* dst = lds_samp + hsl*128;
            int bcol0 = cq * 32;
            if ((unsigned)x0 < 127u) {
                float ys = ynew[k][hsl];
                int y0  = (int)floorf(ys);
                int y0c = min(max(y0, 0), 127), y1c = min(max(y0+1, 0), 127);
                float wa = (float)y1c - ys;     // top tap weight
                float wc = ys - (float)y0c;     // bottom tap weight
                const unsigned short* pb = featbf + ((size_t)b << 20);
                const uint4* p0 = (const uint4*)(pb + (y0c*128 + x0)*64) + cq*2;
                const uint4* p1 = (const uint4*)(pb + (y1c*128 + x0)*64) + cq*2;
#pragma unroll
                for (int ci = 0; ci < 2; ci++) {
                    uint4 a = p0[ci], c = p1[ci];
                    uint4 u;
                    u.x = pack2bf(bflo(a.x)*wa + bflo(c.x)*wc, bfhi(a.x)*wa + bfhi(c.x)*wc);
                    u.y = pack2bf(bflo(a.y)*wa + bflo(c.y)*wc, bfhi(a.y)*wa + bfhi(c.y)*wc);
                    u.z = pack2bf(bflo(a.z)*wa + bflo(c.z)*wc, bfhi(a.z)*wa + bfhi(c.z)*wc);
                    u.w = pack2bf(bflo(a.w)*wa + bflo(c.w)*wc, bfhi(a.w)*wa + bfhi(c.w)*wc);
                    *(uint4*)(dst + ((bcol0 + ci*16) ^ ((hsl & 7) << 4))) = u;
                }
            } else {
                uint4 z = make_uint4(0,0,0,0);
#pragma unroll
                for (int ci = 0; ci < 2; ci++)
                    *(uint4*)(dst + ((bcol0 + ci*16) ^ ((hsl & 7) << 4))) = z;
            }
        }

        // ---- prefetch k+1 weights (latency hides under sync + MFMA) ----
        if (k < 8) {
            const uint4* src = (const uint4*)(wTbf + ((k+1) << 12));
            wv0 = src[t];
            wv1 = src[t + 256];
        }
        __syncthreads();

        // ---- MFMA: acc[ni] += A[16-row tile, 32k-slice] * B ----
#pragma unroll
        for (int ks = 0; ks < 2; ks++) {
            bf16x8 af, bfr[4];
            {
                int hl = m0 + lm;
                af = *(const bf16x8*)(lds_samp + hl*128 + ((ks*64 + lk*16) ^ ((hl & 7) << 4)));
            }
#pragma unroll
            for (int ni = 0; ni < 4; ni++) {
                int o = ni*16 + lm;
                bfr[ni] = *(const bf16x8*)(lds_wk + o*128 + ((ks*64 + lk*16) ^ ((o & 7) << 4)));
            }
#pragma unroll
            for (int ni = 0; ni < 4; ni++)
                acc[ni] = __builtin_amdgcn_mfma_f32_16x16x32_bf16(af, bfr[ni], acc[ni], 0, 0, 0);
        }
    }

    // ---- epilogue: bias, bf16 xpre write (C/D: row=lk*4+reg, col=lm), GN stats ----
#pragma unroll
    for (int ni = 0; ni < 4; ni++) {
        int o = ni*16 + lm;
        float bias = b_dsc[o];
        float4 r;
        r.x = acc[ni][0] + bias;
        r.y = acc[ni][1] + bias;
        r.z = acc[ni][2] + bias;
        r.w = acc[ni][3] + bias;
        float s1 = r.x + r.y + r.z + r.w;
        float s2 = r.x*r.x + r.y*r.y + r.z*r.z + r.w*r.w;
        int hg = hbase + m0 + lk*4;
        uint2 u2;
        u2.x = pack2bf(r.x, r.y);
        u2.y = pack2bf(r.z, r.w);
        *(uint2*)(xprebf + (((b*64 + o) << 14) + (w << 7) + hg)) = u2;

        s1 += __shfl_xor(s1, 1);  s1 += __shfl_xor(s1, 2);
        s1 += __shfl_xor(s1, 16); s1 += __shfl_xor(s1, 32);
        s2 += __shfl_xor(s2, 1);  s2 += __shfl_xor(s2, 2);
        s2 += __shfl_xor(s2, 16); s2 += __shfl_xor(s2, 32);
        if (lk == 0 && (lm & 3) == 0) {
            atomicAdd(&red[ni*4 + (lm >> 2)][0], s1);
            atomicAdd(&red[ni*4 + (lm >> 2)][1], s2);
        }
    }
    __syncthreads();
    if (t < 16) {
        atomicAdd(&gstats[(b*16 + t)*2],   red[t][0]);
        atomicAdd(&gstats[(b*16 + t)*2+1], red[t][1]);
    }
}

// ---------------- GN finalize (folded) + apply + ReLU (bf16 in, fp32 out) ----------------
__global__ __launch_bounds__(256) void k_gn_apply(const unsigned short* __restrict__ xprebf,
                                                  const float* __restrict__ gstats,
                                                  const float* __restrict__ gn_gamma,
                                                  const float* __restrict__ gn_beta,
                                                  float* __restrict__ out) {
    int i8  = blockIdx.x*256 + threadIdx.x;
    int idx = i8 * 8;
    int o = (idx >> 14) & 63;
    int b = idx >> 20;
    int g = o >> 2;
    float n    = 65536.f;           // 4 ch * 128 * 128
    float mean = gstats[(b*16+g)*2] / n;
    float var  = gstats[(b*16+g)*2+1] / n - mean*mean;
    float istd = 1.0f / sqrtf(var + EPS_);
    float ga = gn_gamma[o] * istd;
    float be = gn_beta[o] - mean * ga;
    uint4 v = *(const uint4*)(xprebf + idx);
    float4 r0, r1;
    r0.x = fmaxf(bflo(v.x)*ga + be, 0.f);
    r0.y = fmaxf(bfhi(v.x)*ga + be, 0.f);
    r0.z = fmaxf(bflo(v.y)*ga + be, 0.f);
    r0.w = fmaxf(bfhi(v.y)*ga + be, 0.f);
    r1.x = fmaxf(bflo(v.z)*ga + be, 0.f);
    r1.y = fmaxf(bfhi(v.z)*ga + be, 0.f);
    r1.z = fmaxf(bflo(v.w)*ga + be, 0.f);
    r1.w = fmaxf(bfhi(v.w)*ga + be, 0.f);
    *(float4*)(out + idx)     = r0;
    *(float4*)(out + idx + 4) = r1;
}

extern "C" void kernel_launch(void* const* d_in, const int* in_sizes, int n_in,
                              void* d_out, int out_size, void* d_ws, size_t ws_size,
                              hipStream_t stream) {
    const float* f        = (const float*)d_in[0];
    const float* w_off    = (const float*)d_in[1];
    const float* bn_gamma = (const float*)d_in[3];
    const float* bn_beta  = (const float*)d_in[4];
    const float* w_dsc    = (const float*)d_in[5];
    const float* b_dsc    = (const float*)d_in[6];
    const float* gn_gamma = (const float*)d_in[7];
    const float* gn_beta  = (const float*)d_in[8];

    float* ws      = (float*)d_ws;
    unsigned short* featbf = (unsigned short*)(ws + FEATBF_OFF);
    unsigned short* xprebf = (unsigned short*)(ws + XPRE_OFF);
    float* off_pre = ws + OFFPRE_OFF;
    float* off_half= ws + OFFH_OFF;
    unsigned short* wTbf = (unsigned short*)(ws + WT_OFF);
    float* wP      = ws + WP_OFF;
    float* bnstats = ws + BNSTATS_OFF;
    float* gstats  = ws + GSTATS_OFF;

    hipMemsetAsync(bnstats, 0, STATS_BYTES, stream);

    k_wprep<<<165, 256, 0, stream>>>(w_dsc, wTbf, w_off, wP);
    k_conv_nhwc<<<5120, 128, 0, stream>>>(f, wP, off_half, featbf);
    k_bn_stats<<<288, 256, 0, stream>>>(off_half, off_pre, bnstats);
    k_sample_dsc<<<2048, 256, 0, stream>>>(featbf, off_pre, bnstats, bn_gamma, bn_beta,
                                           wTbf, b_dsc, xprebf, gstats);
    k_gn_apply<<<4096, 256, 0, stream>>>(xprebf, gstats, gn_gamma, gn_beta, (float*)d_out);
}

// Round 19
// 125.701 us; speedup vs baseline: 1.1297x; 1.1297x over previous
//
#include <hip/hip_runtime.h>

#define B_   8
#define C_   64
#define W_   128
#define H_   128
#define K_   9
#define OUT_ 64
#define NPIX (B_*W_*H_)      // 131072
#define EPS_ 1e-5f

typedef __attribute__((ext_vector_type(8))) short bf16x8;
typedef __attribute__((ext_vector_type(4))) float f32x4;

// ---------------- workspace layout (float offsets) ----------------
#define FEATBF_OFF  0                      // B*W*H*C bf16 (4194304 f)
#define XPRE_OFF    4194304                // B*64*W*H bf16 (4194304 f)
#define OFFPRE_OFF  8388608                // B*9*W*H = 1179648
#define OFFH_OFF    9568256                // 4*B*9*W*H = 4718592 (c-split partials)
#define WT_OFF      14286848               // 9*64*64 bf16 (18432 f)
#define WP_OFF      14305280               // 64*81 = 5184
#define BNSTATS_OFF 14310464               // 18
#define GSTATS_OFF  14310500               // 256
#define STATS_BYTES ((18+18+256+256)*sizeof(float))

__device__ __forceinline__ unsigned pack2bf(float a, float b) {
    union { float f; unsigned u; } ua, ub;
    ua.f = a; ub.f = b;
    unsigned x = ua.u, y = ub.u;
    x += 0x7fffu + ((x >> 16) & 1u);       // RNE to bf16
    y += 0x7fffu + ((y >> 16) & 1u);
    return (x >> 16) | (y & 0xffff0000u);
}
__device__ __forceinline__ float bflo(unsigned u) {
    union { unsigned u; float f; } v; v.u = u << 16; return v.f;
}
__device__ __forceinline__ float bfhi(unsigned u) {
    union { unsigned u; float f; } v; v.u = u & 0xffff0000u; return v.f;
}

// ---------------- NCHW -> NHWC bf16 transpose (LDS tile: coalesced BOTH sides) ----------------
// R18 lesson: the LDS-free variant's 128B-stride writes doubled WRITE_SIZE and
// cost ~30us. The LDS transpose is the point of this kernel.
__global__ __launch_bounds__(256) void k_nhwc(const float* __restrict__ f,
                                              unsigned short* __restrict__ featbf) {
    __shared__ float tile[64][65];
    int bid = blockIdx.x;
    int ht = bid & 1;            // 64-high h tile
    int w  = (bid >> 1) & 127;
    int b  = bid >> 8;
    int t  = threadIdx.x;
    int lh = t & 63;
    int c0 = (t >> 6) * 16;
    const float* fp = f + (((b*64)*128 + w)*128) + ht*64 + lh;
#pragma unroll
    for (int i = 0; i < 16; i++) {
        int c = c0 + i;
        tile[c][lh] = fp[c*16384];
    }
    __syncthreads();
    int lc = t & 63;
    int h0 = (t >> 6) * 16;
    unsigned short* obf = featbf + ((size_t)((b*128 + w)*128) + ht*64)*64 + lc;
#pragma unroll
    for (int i = 0; i < 16; i++) {
        int hr = h0 + i;
        union { float f; unsigned u; } v; v.f = tile[lc][hr];
        unsigned x = v.u + 0x7fffu + ((v.u >> 16) & 1u);
        obf[(size_t)hr*64] = (unsigned short)(x >> 16);
    }
}

// ---------------- weight prep: w_dsc -> wTbf[k][o][c] bf16 ; w_off -> wP[c][dw][ck][dh] ----------------
__global__ void k_wprep(const float* __restrict__ w_dsc, unsigned short* __restrict__ wTbf,
                        const float* __restrict__ w_off, float* __restrict__ wP) {
    int bid = blockIdx.x;
    if (bid < 144) {
        int i = bid*256 + threadIdx.x;       // < 36864
        if (i >= 9*64*64) return;
        int c = i & 63;
        int o = (i >> 6) & 63;
        int k = i >> 12;
        union { float f; unsigned u; } v;
        v.f = w_dsc[(o*64 + c)*9 + k];
        unsigned x = v.u + 0x7fffu + ((v.u >> 16) & 1u);
        wTbf[i] = (unsigned short)(x >> 16);
    } else {
        int i = (bid-144)*256 + threadIdx.x; // < 5184
        if (i >= 64*81) return;
        int c    = i / 81;
        int rem  = i % 81;
        int dw   = rem / 27;
        int rem2 = rem % 27;
        int ck   = rem2 / 3;
        int dh   = rem2 % 3;
        wP[i] = w_off[ck*576 + c*9 + dw*3 + dh];
    }
}

// ---------------- 3x3 conv, c-split x4, shuffle taps (NCHW f, lane = h) ----------------
// R13 form — best measured (45us). fp32 path REQUIRED (discontinuous sampler, R7).
// b_off dropped (cancels exactly through BN).
__global__ __launch_bounds__(128) void k_conv_off(const float* __restrict__ f,
                                                  const float* __restrict__ wP,
                                                  float* __restrict__ off_half) {
    int t   = threadIdx.x;          // 0..127 = h
    int bid = blockIdx.x;
    int b   = bid & 7;              // XCD swizzle: each XCD owns one batch
    int w   = (bid >> 3) & 127;     // wave-uniform
    int cq  = bid >> 10;            // c-quarter 0..3 (wave-uniform)
    int h   = t;

    float em = (h == 0)   ? 0.f : 1.f;
    float ep = (h == 127) ? 0.f : 1.f;

    const float* fb = f + (size_t)b*1048576 + (size_t)(cq*16)*16384 + (size_t)w*128;
    const float* wb = wP + cq*16*81;

    float acc[9];
#pragma unroll
    for (int ck = 0; ck < 9; ck++) acc[ck] = 0.f;

#pragma unroll 4
    for (int c = 0; c < 16; c++) {
        const float* p  = fb + c*16384;
        const float* wc = wb + c*81;
#pragma unroll
        for (int dw = -1; dw <= 1; dw++) {
            int wy = w + dw;
            if ((unsigned)wy < 128u) {           // uniform branch
                const float* q = p + dw*128;
                float v1 = q[h];
                float v0 = __shfl_up(v1, 1);
                float v2 = __shfl_down(v1, 1);
                if (t == 64) v0 = q[63];         // cross-wave seam
                if (t == 63) v2 = q[64];
                v0 *= em; v2 *= ep;
                const float* ww = wc + (dw+1)*27;
#pragma unroll
                for (int ck = 0; ck < 9; ck++)
                    acc[ck] += v0*ww[ck*3] + v1*ww[ck*3+1] + v2*ww[ck*3+2];
            }
        }
    }

    float* dst = off_half + (size_t)cq*1179648;
    int pixoff = (w << 7) + h;
#pragma unroll
    for (int ck = 0; ck < 9; ck++)
        dst[((b*9 + ck) << 14) + pixoff] = acc[ck];
}

// ---------------- sum quarters -> off_pre, BN stats ----------------
__global__ __launch_bounds__(256) void k_bn_stats(const float* __restrict__ off_half,
                                                  float* __restrict__ off_pre,
                                                  float* __restrict__ bnstats) {
    __shared__ float wred[4][2];
    int bid = blockIdx.x;           // 288 = b*36 + ck*4 + wq
    int b  = bid / 36;
    int rem = bid % 36;
    int ck = rem / 4;
    int wq = rem % 4;
    int t  = threadIdx.x;
    int base4 = (((b*9+ck) << 14) + wq*4096) >> 2;

    const float4* h0 = (const float4*)off_half;
    const float4* h1 = (const float4*)(off_half + 1179648);
    const float4* h2 = (const float4*)(off_half + 2359296);
    const float4* h3 = (const float4*)(off_half + 3538944);
    float4* op = (float4*)off_pre;

    float s = 0.f, q = 0.f;
#pragma unroll
    for (int i = 0; i < 4; i++) {
        int idx = base4 + t + i*256;
        float4 a = h0[idx], bb = h1[idx], cc = h2[idx], dd = h3[idx];
        float4 v;
        v.x = (a.x + bb.x) + (cc.x + dd.x);
        v.y = (a.y + bb.y) + (cc.y + dd.y);
        v.z = (a.z + bb.z) + (cc.z + dd.z);
        v.w = (a.w + bb.w) + (cc.w + dd.w);
        op[idx] = v;
        s += v.x + v.y + v.z + v.w;
        q += v.x*v.x + v.y*v.y + v.z*v.z + v.w*v.w;
    }
    for (int off = 32; off; off >>= 1) {
        s += __shfl_down(s, off);
        q += __shfl_down(q, off);
    }
    if ((t & 63) == 0) { wred[t >> 6][0] = s; wred[t >> 6][1] = q; }
    __syncthreads();
    if (t == 0) atomicAdd(&bnstats[ck*2],   wred[0][0]+wred[1][0]+wred[2][0]+wred[3][0]);
    if (t == 1) atomicAdd(&bnstats[ck*2+1], wred[0][1]+wred[1][1]+wred[2][1]+wred[3][1]);
}

// ---------------- fused: BN-finalize, offsets, 2-tap sample (bf16), MFMA, GN stats ----------------
// M-split x2: block = (b, w, h-half of 64 rows); 2048 blocks, 18.9KB LDS.
__global__ __launch_bounds__(256) void k_sample_dsc(const unsigned short* __restrict__ featbf,
                                                    const float* __restrict__ off_pre,
                                                    const float* __restrict__ bnstats,
                                                    const float* __restrict__ bn_gamma,
                                                    const float* __restrict__ bn_beta,
                                                    const unsigned short* __restrict__ wTbf,
                                                    const float* __restrict__ b_dsc,
                                                    unsigned short* __restrict__ xprebf,
                                                    float* __restrict__ gstats) {
    __shared__ __align__(16) unsigned char lds_samp[64*128]; // [h][c] bf16, XOR-swizzled rows
    __shared__ __align__(16) unsigned char lds_wk[64*128];   // [o][c] bf16, XOR-swizzled rows
    __shared__ float ynew[9][64];
    __shared__ float red[16][2];
    __shared__ float bnab[18];

    int t = threadIdx.x;
    int bid = blockIdx.x;              // 2048 = mh*1024 + w*8 + b
    int b = bid & 7, w = (bid >> 3) & 127, mh = bid >> 10;
    int hbase = mh * 64;

    // BN finalize (folded): per-block recompute, trivial
    if (t < 9) {
        float n    = (float)NPIX;
        float mean = bnstats[t*2] / n;
        float var  = bnstats[t*2+1] / n - mean*mean;
        float A    = bn_gamma[t] / sqrtf(var + EPS_);
        bnab[t*2]   = A;
        bnab[t*2+1] = bn_beta[t] - mean * A;
    }
    if (t < 16) { red[t][0] = 0.f; red[t][1] = 0.f; }
    __syncthreads();

    if (t < 64) {
        int h = hbase + t;
        float y[9];
#pragma unroll
        for (int ck = 0; ck < 9; ck++) {
            float v = off_pre[((b*9+ck) << 14) + (w << 7) + h];
            y[ck] = tanhf(bnab[ck*2]*v + bnab[ck*2+1]);
        }
        float ofn[9];
        ofn[4] = 0.f;
        ofn[5] = y[5]; ofn[6] = y[5]+y[6]; ofn[7] = y[5]+y[6]+y[7];
        ofn[3] = y[3]; ofn[2] = y[3]+y[2]; ofn[1] = y[3]+y[2]+y[1];
        ofn[0] = y[0]; ofn[8] = y[8];
#pragma unroll
        for (int k = 0; k < 9; k++) ynew[k][t] = (float)w + ofn[k];
    }

    f32x4 acc[4];
#pragma unroll
    for (int ni = 0; ni < 4; ni++) {
        acc[ni][0] = 0.f; acc[ni][1] = 0.f; acc[ni][2] = 0.f; acc[ni][3] = 0.f;
    }

    int lane = t & 63, wv = t >> 6;
    int m0 = wv * 16;                 // wave's local 16-row M tile
    int lm = lane & 15, lk = lane >> 4;
    int hsl = t >> 2;                 // local sampling row 0..63
    int cq  = t & 3;                  // quarter of the 128B row (16 ch)

    // prefetch k=0 weights into regs
    uint4 wv0, wv1;
    {
        const uint4* src = (const uint4*)wTbf;
        wv0 = src[t];
        wv1 = src[t + 256];
    }

    __syncthreads();

    for (int k = 0; k < 9; k++) {
        if (k) __syncthreads();       // previous iter's MFMA reads done

        // ---- write prefetched weight k-slice [64 o][64 c] bf16 into swizzled LDS ----
        {
#pragma unroll
            for (int i = 0; i < 2; i++) {
                int ci = t + i*256;                 // 0..511 16B chunks
                uint4 v = (i == 0) ? wv0 : wv1;
                int o  = ci >> 3;
                int cb = (ci & 7) << 4;
                *(uint4*)(lds_wk + o*128 + (cb ^ ((o & 7) << 4))) = v;
            }
        }

        // ---- 2-tap y-lerp sample, local row hsl (4 threads/row), 16 ch each ----
        // x_s is integer -> x-weights are {1,0} in-bounds, exact 0 outside
        {
            int hg = hbase + hsl;
            int x0 = k - 4 + hg;
            unsigned char* dst = lds_samp + hsl*128;
            int bcol0 = cq * 32;
            if ((unsigned)x0 < 127u) {
                float ys = ynew[k][hsl];
                int y0  = (int)floorf(ys);
                int y0c = min(max(y0, 0), 127), y1c = min(max(y0+1, 0), 127);
                float wa = (float)y1c - ys;     // top tap weight
                float wc = ys - (float)y0c;     // bottom tap weight
                const unsigned short* pb = featbf + ((size_t)b << 20);
                const uint4* p0 = (const uint4*)(pb + (y0c*128 + x0)*64) + cq*2;
                const uint4* p1 = (const uint4*)(pb + (y1c*128 + x0)*64) + cq*2;
#pragma unroll
                for (int ci = 0; ci < 2; ci++) {
                    uint4 a = p0[ci], c = p1[ci];
                    uint4 u;
                    u.x = pack2bf(bflo(a.x)*wa + bflo(c.x)*wc, bfhi(a.x)*wa + bfhi(c.x)*wc);
                    u.y = pack2bf(bflo(a.y)*wa + bflo(c.y)*wc, bfhi(a.y)*wa + bfhi(c.y)*wc);
                    u.z = pack2bf(bflo(a.z)*wa + bflo(c.z)*wc, bfhi(a.z)*wa + bfhi(c.z)*wc);
                    u.w = pack2bf(bflo(a.w)*wa + bflo(c.w)*wc, bfhi(a.w)*wa + bfhi(c.w)*wc);
                    *(uint4*)(dst + ((bcol0 + ci*16) ^ ((hsl & 7) << 4))) = u;
                }
            } else {
                uint4 z = make_uint4(0,0,0,0);
#pragma unroll
                for (int ci = 0; ci < 2; ci++)
                    *(uint4*)(dst + ((bcol0 + ci*16) ^ ((hsl & 7) << 4))) = z;
            }
        }

        // ---- prefetch k+1 weights (latency hides under sync + MFMA) ----
        if (k < 8) {
            const uint4* src = (const uint4*)(wTbf + ((k+1) << 12));
            wv0 = src[t];
            wv1 = src[t + 256];
        }
        __syncthreads();

        // ---- MFMA: acc[ni] += A[16-row tile, 32k-slice] * B ----
#pragma unroll
        for (int ks = 0; ks < 2; ks++) {
            bf16x8 af, bfr[4];
            {
                int hl = m0 + lm;
                af = *(const bf16x8*)(lds_samp + hl*128 + ((ks*64 + lk*16) ^ ((hl & 7) << 4)));
            }
#pragma unroll
            for (int ni = 0; ni < 4; ni++) {
                int o = ni*16 + lm;
                bfr[ni] = *(const bf16x8*)(lds_wk + o*128 + ((ks*64 + lk*16) ^ ((o & 7) << 4)));
            }
#pragma unroll
            for (int ni = 0; ni < 4; ni++)
                acc[ni] = __builtin_amdgcn_mfma_f32_16x16x32_bf16(af, bfr[ni], acc[ni], 0, 0, 0);
        }
    }

    // ---- epilogue: bias, bf16 xpre write (C/D: row=lk*4+reg, col=lm), GN stats ----
#pragma unroll
    for (int ni = 0; ni < 4; ni++) {
        int o = ni*16 + lm;
        float bias = b_dsc[o];
        float4 r;
        r.x = acc[ni][0] + bias;
        r.y = acc[ni][1] + bias;
        r.z = acc[ni][2] + bias;
        r.w = acc[ni][3] + bias;
        float s1 = r.x + r.y + r.z + r.w;
        float s2 = r.x*r.x + r.y*r.y + r.z*r.z + r.w*r.w;
        int hg = hbase + m0 + lk*4;
        uint2 u2;
        u2.x = pack2bf(r.x, r.y);
        u2.y = pack2bf(r.z, r.w);
        *(uint2*)(xprebf + (((b*64 + o) << 14) + (w << 7) + hg)) = u2;

        s1 += __shfl_xor(s1, 1);  s1 += __shfl_xor(s1, 2);
        s1 += __shfl_xor(s1, 16); s1 += __shfl_xor(s1, 32);
        s2 += __shfl_xor(s2, 1);  s2 += __shfl_xor(s2, 2);
        s2 += __shfl_xor(s2, 16); s2 += __shfl_xor(s2, 32);
        if (lk == 0 && (lm & 3) == 0) {
            atomicAdd(&red[ni*4 + (lm >> 2)][0], s1);
            atomicAdd(&red[ni*4 + (lm >> 2)][1], s2);
        }
    }
    __syncthreads();
    if (t < 16) {
        atomicAdd(&gstats[(b*16 + t)*2],   red[t][0]);
        atomicAdd(&gstats[(b*16 + t)*2+1], red[t][1]);
    }
}

// ---------------- GN finalize (folded) + apply + ReLU (bf16 in, fp32 out) ----------------
__global__ __launch_bounds__(256) void k_gn_apply(const unsigned short* __restrict__ xprebf,
                                                  const float* __restrict__ gstats,
                                                  const float* __restrict__ gn_gamma,
                                                  const float* __restrict__ gn_beta,
                                                  float* __restrict__ out) {
    int i8  = blockIdx.x*256 + threadIdx.x;
    int idx = i8 * 8;
    int o = (idx >> 14) & 63;
    int b = idx >> 20;
    int g = o >> 2;
    float n    = 65536.f;           // 4 ch * 128 * 128
    float mean = gstats[(b*16+g)*2] / n;
    float var  = gstats[(b*16+g)*2+1] / n - mean*mean;
    float istd = 1.0f / sqrtf(var + EPS_);
    float ga = gn_gamma[o] * istd;
    float be = gn_beta[o] - mean * ga;
    uint4 v = *(const uint4*)(xprebf + idx);
    float4 r0, r1;
    r0.x = fmaxf(bflo(v.x)*ga + be, 0.f);
    r0.y = fmaxf(bfhi(v.x)*ga + be, 0.f);
    r0.z = fmaxf(bflo(v.y)*ga + be, 0.f);
    r0.w = fmaxf(bfhi(v.y)*ga + be, 0.f);
    r1.x = fmaxf(bflo(v.z)*ga + be, 0.f);
    r1.y = fmaxf(bfhi(v.z)*ga + be, 0.f);
    r1.z = fmaxf(bflo(v.w)*ga + be, 0.f);
    r1.w = fmaxf(bfhi(v.w)*ga + be, 0.f);
    *(float4*)(out + idx)     = r0;
    *(float4*)(out + idx + 4) = r1;
}

extern "C" void kernel_launch(void* const* d_in, const int* in_sizes, int n_in,
                              void* d_out, int out_size, void* d_ws, size_t ws_size,
                              hipStream_t stream) {
    const float* f        = (const float*)d_in[0];
    const float* w_off    = (const float*)d_in[1];
    const float* bn_gamma = (const float*)d_in[3];
    const float* bn_beta  = (const float*)d_in[4];
    const float* w_dsc    = (const float*)d_in[5];
    const float* b_dsc    = (const float*)d_in[6];
    const float* gn_gamma = (const float*)d_in[7];
    const float* gn_beta  = (const float*)d_in[8];

    float* ws      = (float*)d_ws;
    unsigned short* featbf = (unsigned short*)(ws + FEATBF_OFF);
    unsigned short* xprebf = (unsigned short*)(ws + XPRE_OFF);
    float* off_pre = ws + OFFPRE_OFF;
    float* off_half= ws + OFFH_OFF;
    unsigned short* wTbf = (unsigned short*)(ws + WT_OFF);
    float* wP      = ws + WP_OFF;
    float* bnstats = ws + BNSTATS_OFF;
    float* gstats  = ws + GSTATS_OFF;

    hipMemsetAsync(bnstats, 0, STATS_BYTES, stream);

    k_nhwc<<<2048, 256, 0, stream>>>(f, featbf);
    k_wprep<<<165, 256, 0, stream>>>(w_dsc, wTbf, w_off, wP);
    k_conv_off<<<4096, 128, 0, stream>>>(f, wP, off_half);
    k_bn_stats<<<288, 256, 0, stream>>>(off_half, off_pre, bnstats);
    k_sample_dsc<<<2048, 256, 0, stream>>>(featbf, off_pre, bnstats, bn_gamma, bn_beta,
                                           wTbf, b_dsc, xprebf, gstats);
    k_gn_apply<<<4096, 256, 0, stream>>>(xprebf, gstats, gn_gamma, gn_beta, (float*)d_out);
}

// Round 21
// 125.499 us; speedup vs baseline: 1.1315x; 1.0016x over previous
//
#include <hip/hip_runtime.h>

#define B_   8
#define C_   64
#define W_   128
#define H_   128
#define K_   9
#define OUT_ 64
#define NPIX (B_*W_*H_)      // 131072
#define EPS_ 1e-5f

typedef __attribute__((ext_vector_type(8))) short bf16x8;
typedef __attribute__((ext_vector_type(4))) float f32x4;

// ---------------- workspace layout (float offsets) ----------------
#define FEATBF_OFF  0                      // B*W*H*C bf16 (4194304 f)
#define XPRE_OFF    4194304                // B*64*W*H bf16 (4194304 f)
#define OFFPRE_OFF  8388608                // B*9*W*H = 1179648
#define OFFH_OFF    9568256                // 4*B*9*W*H = 4718592 (c-split partials)
#define WT_OFF      14286848               // 9*64*64 bf16 (18432 f)
#define WP_OFF      14305280               // 64*81 = 5184
#define BNSTATS_OFF 14310464               // 18
#define GSTATS_OFF  14310500               // 256
#define STATS_BYTES ((18+18+256+256)*sizeof(float))

__device__ __forceinline__ unsigned pack2bf(float a, float b) {
    union { float f; unsigned u; } ua, ub;
    ua.f = a; ub.f = b;
    unsigned x = ua.u, y = ub.u;
    x += 0x7fffu + ((x >> 16) & 1u);       // RNE to bf16
    y += 0x7fffu + ((y >> 16) & 1u);
    return (x >> 16) | (y & 0xffff0000u);
}
__device__ __forceinline__ float bflo(unsigned u) {
    union { unsigned u; float f; } v; v.u = u << 16; return v.f;
}
__device__ __forceinline__ float bfhi(unsigned u) {
    union { unsigned u; float f; } v; v.u = u & 0xffff0000u; return v.f;
}

// ---------------- NCHW -> NHWC bf16 transpose (LDS tile: coalesced BOTH sides) ----------------
__global__ __launch_bounds__(256) void k_nhwc(const float* __restrict__ f,
                                              unsigned short* __restrict__ featbf) {
    __shared__ float tile[64][65];
    int bid = blockIdx.x;
    int ht = bid & 1;            // 64-high h tile
    int w  = (bid >> 1) & 127;
    int b  = bid >> 8;
    int t  = threadIdx.x;
    int lh = t & 63;
    int c0 = (t >> 6) * 16;
    const float* fp = f + (((b*64)*128 + w)*128) + ht*64 + lh;
#pragma unroll
    for (int i = 0; i < 16; i++) {
        int c = c0 + i;
        tile[c][lh] = fp[c*16384];
    }
    __syncthreads();
    int lc = t & 63;
    int h0 = (t >> 6) * 16;
    unsigned short* obf = featbf + ((size_t)((b*128 + w)*128) + ht*64)*64 + lc;
#pragma unroll
    for (int i = 0; i < 16; i++) {
        int hr = h0 + i;
        union { float f; unsigned u; } v; v.f = tile[lc][hr];
        unsigned x = v.u + 0x7fffu + ((v.u >> 16) & 1u);
        obf[(size_t)hr*64] = (unsigned short)(x >> 16);
    }
}

// ---------------- weight prep: w_dsc -> wTbf[k][o][c] bf16 ; w_off -> wP[c][dw][ck][dh] ----------------
__global__ void k_wprep(const float* __restrict__ w_dsc, unsigned short* __restrict__ wTbf,
                        const float* __restrict__ w_off, float* __restrict__ wP) {
    int bid = blockIdx.x;
    if (bid < 144) {
        int i = bid*256 + threadIdx.x;       // < 36864
        if (i >= 9*64*64) return;
        int c = i & 63;
        int o = (i >> 6) & 63;
        int k = i >> 12;
        union { float f; unsigned u; } v;
        v.f = w_dsc[(o*64 + c)*9 + k];
        unsigned x = v.u + 0x7fffu + ((v.u >> 16) & 1u);
        wTbf[i] = (unsigned short)(x >> 16);
    } else {
        int i = (bid-144)*256 + threadIdx.x; // < 5184
        if (i >= 64*81) return;
        int c    = i / 81;
        int rem  = i % 81;
        int dw   = rem / 27;
        int rem2 = rem % 27;
        int ck   = rem2 / 3;
        int dh   = rem2 % 3;
        wP[i] = w_off[ck*576 + c*9 + dw*3 + dh];
    }
}

// ---------------- 3x3 conv, c-split x4, shuffle taps (NCHW f, lane = h) ----------------
// R13 form — best measured (45us). fp32 path REQUIRED (discontinuous sampler, R7).
// b_off dropped (cancels exactly through BN).
__global__ __launch_bounds__(128) void k_conv_off(const float* __restrict__ f,
                                                  const float* __restrict__ wP,
                                                  float* __restrict__ off_half) {
    int t   = threadIdx.x;          // 0..127 = h
    int bid = blockIdx.x;
    int b   = bid & 7;              // XCD swizzle: each XCD owns one batch
    int w   = (bid >> 3) & 127;     // wave-uniform
    int cq  = bid >> 10;            // c-quarter 0..3 (wave-uniform)
    int h   = t;

    float em = (h == 0)   ? 0.f : 1.f;
    float ep = (h == 127) ? 0.f : 1.f;

    const float* fb = f + (size_t)b*1048576 + (size_t)(cq*16)*16384 + (size_t)w*128;
    const float* wb = wP + cq*16*81;

    float acc[9];
#pragma unroll
    for (int ck = 0; ck < 9; ck++) acc[ck] = 0.f;

#pragma unroll 4
    for (int c = 0; c < 16; c++) {
        const float* p  = fb + c*16384;
        const float* wc = wb + c*81;
#pragma unroll
        for (int dw = -1; dw <= 1; dw++) {
            int wy = w + dw;
            if ((unsigned)wy < 128u) {           // uniform branch
                const float* q = p + dw*128;
                float v1 = q[h];
                float v0 = __shfl_up(v1, 1);
                float v2 = __shfl_down(v1, 1);
                if (t == 64) v0 = q[63];         // cross-wave seam
                if (t == 63) v2 = q[64];
                v0 *= em; v2 *= ep;
                const float* ww = wc + (dw+1)*27;
#pragma unroll
                for (int ck = 0; ck < 9; ck++)
                    acc[ck] += v0*ww[ck*3] + v1*ww[ck*3+1] + v2*ww[ck*3+2];
            }
        }
    }

    float* dst = off_half + (size_t)cq*1179648;
    int pixoff = (w << 7) + h;
#pragma unroll
    for (int ck = 0; ck < 9; ck++)
        dst[((b*9 + ck) << 14) + pixoff] = acc[ck];
}

// ---------------- sum quarters -> off_pre, BN stats ----------------
__global__ __launch_bounds__(256) void k_bn_stats(const float* __restrict__ off_half,
                                                  float* __restrict__ off_pre,
                                                  float* __restrict__ bnstats) {
    __shared__ float wred[4][2];
    int bid = blockIdx.x;           // 288 = b*36 + ck*4 + wq
    int b  = bid / 36;
    int rem = bid % 36;
    int ck = rem / 4;
    int wq = rem % 4;
    int t  = threadIdx.x;
    int base4 = (((b*9+ck) << 14) + wq*4096) >> 2;

    const float4* h0 = (const float4*)off_half;
    const float4* h1 = (const float4*)(off_half + 1179648);
    const float4* h2 = (const float4*)(off_half + 2359296);
    const float4* h3 = (const float4*)(off_half + 3538944);
    float4* op = (float4*)off_pre;

    float s = 0.f, q = 0.f;
#pragma unroll
    for (int i = 0; i < 4; i++) {
        int idx = base4 + t + i*256;
        float4 a = h0[idx], bb = h1[idx], cc = h2[idx], dd = h3[idx];
        float4 v;
        v.x = (a.x + bb.x) + (cc.x + dd.x);
        v.y = (a.y + bb.y) + (cc.y + dd.y);
        v.z = (a.z + bb.z) + (cc.z + dd.z);
        v.w = (a.w + bb.w) + (cc.w + dd.w);
        op[idx] = v;
        s += v.x + v.y + v.z + v.w;
        q += v.x*v.x + v.y*v.y + v.z*v.z + v.w*v.w;
    }
    for (int off = 32; off; off >>= 1) {
        s += __shfl_down(s, off);
        q += __shfl_down(q, off);
    }
    if ((t & 63) == 0) { wred[t >> 6][0] = s; wred[t >> 6][1] = q; }
    __syncthreads();
    if (t == 0) atomicAdd(&bnstats[ck*2],   wred[0][0]+wred[1][0]+wred[2][0]+wred[3][0]);
    if (t == 1) atomicAdd(&bnstats[ck*2+1], wred[0][1]+wred[1][1]+wred[2][1]+wred[3][1]);
}

// ---------------- fused: BN-finalize, offsets, sample, MFMA, GN stats ----------------
// Double-buffered LDS, ONE barrier per k (R19: 2 barriers/k each forced a
// vmcnt(0) drain of the gather loads -> 49us invariant to occupancy).
// Pipeline: issue loads(k+1) -> MFMA(k) hides latency -> blend+write(k+1) -> barrier.
__global__ __launch_bounds__(256) void k_sample_dsc(const unsigned short* __restrict__ featbf,
                                                    const float* __restrict__ off_pre,
                                                    const float* __restrict__ bnstats,
                                                    const float* __restrict__ bn_gamma,
                                                    const float* __restrict__ bn_beta,
                                                    const unsigned short* __restrict__ wTbf,
                                                    const float* __restrict__ b_dsc,
                                                    unsigned short* __restrict__ xprebf,
                                                    float* __restrict__ gstats) {
    __shared__ __align__(16) unsigned char lds_samp[2][64*128]; // [h][c] bf16, XOR-swizzled
    __shared__ __align__(16) unsigned char lds_wk[2][64*128];   // [o][c] bf16, XOR-swizzled
    __shared__ float ynew[9][64];
    __shared__ float red[16][2];
    __shared__ float bnab[18];

    int t = threadIdx.x;
    int bid = blockIdx.x;              // 2048 = mh*1024 + w*8 + b
    int b = bid & 7, w = (bid >> 3) & 127, mh = bid >> 10;
    int hbase = mh * 64;

    if (t < 9) {
        float n    = (float)NPIX;
        float mean = bnstats[t*2] / n;
        float var  = bnstats[t*2+1] / n - mean*mean;
        float A    = bn_gamma[t] / sqrtf(var + EPS_);
        bnab[t*2]   = A;
        bnab[t*2+1] = bn_beta[t] - mean * A;
    }
    if (t < 16) { red[t][0] = 0.f; red[t][1] = 0.f; }
    __syncthreads();

    if (t < 64) {
        int h = hbase + t;
        float y[9];
#pragma unroll
        for (int ck = 0; ck < 9; ck++) {
            float v = off_pre[((b*9+ck) << 14) + (w << 7) + h];
            y[ck] = tanhf(bnab[ck*2]*v + bnab[ck*2+1]);
        }
        float ofn[9];
        ofn[4] = 0.f;
        ofn[5] = y[5]; ofn[6] = y[5]+y[6]; ofn[7] = y[5]+y[6]+y[7];
        ofn[3] = y[3]; ofn[2] = y[3]+y[2]; ofn[1] = y[3]+y[2]+y[1];
        ofn[0] = y[0]; ofn[8] = y[8];
#pragma unroll
        for (int k = 0; k < 9; k++) ynew[k][t] = (float)w + ofn[k];
    }
    __syncthreads();                  // ynew ready for stage(k=0)

    f32x4 acc[4];
#pragma unroll
    for (int ni = 0; ni < 4; ni++) {
        acc[ni][0] = 0.f; acc[ni][1] = 0.f; acc[ni][2] = 0.f; acc[ni][3] = 0.f;
    }

    int lane = t & 63, wv = t >> 6;
    int m0 = wv * 16;                 // wave's local 16-row M tile
    int lm = lane & 15, lk = lane >> 4;
    int hsl = t >> 2;                 // local sampling row 0..63
    int cq  = t & 3;                  // quarter of the 128B row (16 ch)
    const unsigned short* pbase = featbf + ((size_t)b << 20);

    uint4 sa0, sa1, sb0, sb1, wv0, wv1;
    float twa = 0.f, twc = 0.f;
    bool valid = false;

    // ---- stage k=0: load ----
    {
        int hg = hbase + hsl;
        int x0 = 0 - 4 + hg;
        valid = (unsigned)x0 < 127u;
        if (valid) {
            float ys = ynew[0][hsl];
            int y0  = (int)floorf(ys);
            int y0c = min(max(y0, 0), 127), y1c = min(max(y0+1, 0), 127);
            twa = (float)y1c - ys; twc = ys - (float)y0c;
            const uint4* p0 = (const uint4*)(pbase + (y0c*128 + x0)*64) + cq*2;
            const uint4* p1 = (const uint4*)(pbase + (y1c*128 + x0)*64) + cq*2;
            sa0 = p0[0]; sa1 = p0[1];
            sb0 = p1[0]; sb1 = p1[1];
        }
        const uint4* src = (const uint4*)wTbf;
        wv0 = src[t]; wv1 = src[t + 256];
    }
    // ---- stage k=0: write into buf 0 ----
    {
        unsigned char* dst = lds_samp[0] + hsl*128;
        int bcol0 = cq * 32;
        uint4 u0 = make_uint4(0,0,0,0), u1 = make_uint4(0,0,0,0);
        if (valid) {
            u0.x = pack2bf(bflo(sa0.x)*twa + bflo(sb0.x)*twc, bfhi(sa0.x)*twa + bfhi(sb0.x)*twc);
            u0.y = pack2bf(bflo(sa0.y)*twa + bflo(sb0.y)*twc, bfhi(sa0.y)*twa + bfhi(sb0.y)*twc);
            u0.z = pack2bf(bflo(sa0.z)*twa + bflo(sb0.z)*twc, bfhi(sa0.z)*twa + bfhi(sb0.z)*twc);
            u0.w = pack2bf(bflo(sa0.w)*twa + bflo(sb0.w)*twc, bfhi(sa0.w)*twa + bfhi(sb0.w)*twc);
            u1.x = pack2bf(bflo(sa1.x)*twa + bflo(sb1.x)*twc, bfhi(sa1.x)*twa + bfhi(sb1.x)*twc);
            u1.y = pack2bf(bflo(sa1.y)*twa + bflo(sb1.y)*twc, bfhi(sa1.y)*twa + bfhi(sb1.y)*twc);
            u1.z = pack2bf(bflo(sa1.z)*twa + bflo(sb1.z)*twc, bfhi(sa1.z)*twa + bfhi(sb1.z)*twc);
            u1.w = pack2bf(bflo(sa1.w)*twa + bflo(sb1.w)*twc, bfhi(sa1.w)*twa + bfhi(sb1.w)*twc);
        }
        *(uint4*)(dst + ((bcol0     ) ^ ((hsl & 7) << 4))) = u0;
        *(uint4*)(dst + ((bcol0 + 16) ^ ((hsl & 7) << 4))) = u1;
#pragma unroll
        for (int i = 0; i < 2; i++) {
            int ci = t + i*256;
            uint4 v = (i == 0) ? wv0 : wv1;
            int o  = ci >> 3;
            int cb = (ci & 7) << 4;
            *(uint4*)(lds_wk[0] + o*128 + (cb ^ ((o & 7) << 4))) = v;
        }
    }
    __syncthreads();

    for (int k = 0; k < 9; k++) {
        int cur = k & 1, nxt = cur ^ 1;

        // ---- issue loads for k+1 (latency hides under MFMA below) ----
        if (k < 8) {
            int hg = hbase + hsl;
            int x0 = (k+1) - 4 + hg;
            valid = (unsigned)x0 < 127u;
            if (valid) {
                float ys = ynew[k+1][hsl];
                int y0  = (int)floorf(ys);
                int y0c = min(max(y0, 0), 127), y1c = min(max(y0+1, 0), 127);
                twa = (float)y1c - ys; twc = ys - (float)y0c;
                const uint4* p0 = (const uint4*)(pbase + (y0c*128 + x0)*64) + cq*2;
                const uint4* p1 = (const uint4*)(pbase + (y1c*128 + x0)*64) + cq*2;
                sa0 = p0[0]; sa1 = p0[1];
                sb0 = p1[0]; sb1 = p1[1];
            }
            const uint4* src = (const uint4*)(wTbf + ((k+1) << 12));
            wv0 = src[t]; wv1 = src[t + 256];
        }

        // ---- MFMA(k) from buf[cur] ----
#pragma unroll
        for (int ks = 0; ks < 2; ks++) {
            bf16x8 af, bfr[4];
            {
                int hl = m0 + lm;
                af = *(const bf16x8*)(lds_samp[cur] + hl*128 + ((ks*64 + lk*16) ^ ((hl & 7) << 4)));
            }
#pragma unroll
            for (int ni = 0; ni < 4; ni++) {
                int o = ni*16 + lm;
                bfr[ni] = *(const bf16x8*)(lds_wk[cur] + o*128 + ((ks*64 + lk*16) ^ ((o & 7) << 4)));
            }
#pragma unroll
            for (int ni = 0; ni < 4; ni++)
                acc[ni] = __builtin_amdgcn_mfma_f32_16x16x32_bf16(af, bfr[ni], acc[ni], 0, 0, 0);
        }

        // ---- blend + write k+1 into buf[nxt] ----
        if (k < 8) {
            unsigned char* dst = lds_samp[nxt] + hsl*128;
            int bcol0 = cq * 32;
            uint4 u0 = make_uint4(0,0,0,0), u1 = make_uint4(0,0,0,0);
            if (valid) {
                u0.x = pack2bf(bflo(sa0.x)*twa + bflo(sb0.x)*twc, bfhi(sa0.x)*twa + bfhi(sb0.x)*twc);
                u0.y = pack2bf(bflo(sa0.y)*twa + bflo(sb0.y)*twc, bfhi(sa0.y)*twa + bfhi(sb0.y)*twc);
                u0.z = pack2bf(bflo(sa0.z)*twa + bflo(sb0.z)*twc, bfhi(sa0.z)*twa + bfhi(sb0.z)*twc);
                u0.w = pack2bf(bflo(sa0.w)*twa + bflo(sb0.w)*twc, bfhi(sa0.w)*twa + bfhi(sb0.w)*twc);
                u1.x = pack2bf(bflo(sa1.x)*twa + bflo(sb1.x)*twc, bfhi(sa1.x)*twa + bfhi(sb1.x)*twc);
                u1.y = pack2bf(bflo(sa1.y)*twa + bflo(sb1.y)*twc, bfhi(sa1.y)*twa + bfhi(sb1.y)*twc);
                u1.z = pack2bf(bflo(sa1.z)*twa + bflo(sb1.z)*twc, bfhi(sa1.z)*twa + bfhi(sb1.z)*twc);
                u1.w = pack2bf(bflo(sa1.w)*twa + bflo(sb1.w)*twc, bfhi(sa1.w)*twa + bfhi(sb1.w)*twc);
            }
            *(uint4*)(dst + ((bcol0     ) ^ ((hsl & 7) << 4))) = u0;
            *(uint4*)(dst + ((bcol0 + 16) ^ ((hsl & 7) << 4))) = u1;
#pragma unroll
            for (int i = 0; i < 2; i++) {
                int ci = t + i*256;
                uint4 v = (i == 0) ? wv0 : wv1;
                int o  = ci >> 3;
                int cb = (ci & 7) << 4;
                *(uint4*)(lds_wk[nxt] + o*128 + (cb ^ ((o & 7) << 4))) = v;
            }
            __syncthreads();
        }
    }

    // ---- epilogue: bias, bf16 xpre write (C/D: row=lk*4+reg, col=lm), GN stats ----
#pragma unroll
    for (int ni = 0; ni < 4; ni++) {
        int o = ni*16 + lm;
        float bias = b_dsc[o];
        float4 r;
        r.x = acc[ni][0] + bias;
        r.y = acc[ni][1] + bias;
        r.z = acc[ni][2] + bias;
        r.w = acc[ni][3] + bias;
        float s1 = r.x + r.y + r.z + r.w;
        float s2 = r.x*r.x + r.y*r.y + r.z*r.z + r.w*r.w;
        int hg = hbase + m0 + lk*4;
        uint2 u2;
        u2.x = pack2bf(r.x, r.y);
        u2.y = pack2bf(r.z, r.w);
        *(uint2*)(xprebf + (((b*64 + o) << 14) + (w << 7) + hg)) = u2;

        s1 += __shfl_xor(s1, 1);  s1 += __shfl_xor(s1, 2);
        s1 += __shfl_xor(s1, 16); s1 += __shfl_xor(s1, 32);
        s2 += __shfl_xor(s2, 1);  s2 += __shfl_xor(s2, 2);
        s2 += __shfl_xor(s2, 16); s2 += __shfl_xor(s2, 32);
        if (lk == 0 && (lm & 3) == 0) {
            atomicAdd(&red[ni*4 + (lm >> 2)][0], s1);
            atomicAdd(&red[ni*4 + (lm >> 2)][1], s2);
        }
    }
    __syncthreads();
    if (t < 16) {
        atomicAdd(&gstats[(b*16 + t)*2],   red[t][0]);
        atomicAdd(&gstats[(b*16 + t)*2+1], red[t][1]);
    }
}

// ---------------- GN finalize (folded) + apply + ReLU (bf16 in, fp32 out) ----------------
__global__ __launch_bounds__(256) void k_gn_apply(const unsigned short* __restrict__ xprebf,
                                                  const float* __restrict__ gstats,
                                                  const float* __restrict__ gn_gamma,
                                                  const float* __restrict__ gn_beta,
                                                  float* __restrict__ out) {
    int i8  = blockIdx.x*256 + threadIdx.x;
    int idx = i8 * 8;
    int o = (idx >> 14) & 63;
    int b = idx >> 20;
    int g = o >> 2;
    float n    = 65536.f;           // 4 ch * 128 * 128
    float mean = gstats[(b*16+g)*2] / n;
    float var  = gstats[(b*16+g)*2+1] / n - mean*mean;
    float istd = 1.0f / sqrtf(var + EPS_);
    float ga = gn_gamma[o] * istd;
    float be = gn_beta[o] - mean * ga;
    uint4 v = *(const uint4*)(xprebf + idx);
    float4 r0, r1;
    r0.x = fmaxf(bflo(v.x)*ga + be, 0.f);
    r0.y = fmaxf(bfhi(v.x)*ga + be, 0.f);
    r0.z = fmaxf(bflo(v.y)*ga + be, 0.f);
    r0.w = fmaxf(bfhi(v.y)*ga + be, 0.f);
    r1.x = fmaxf(bflo(v.z)*ga + be, 0.f);
    r1.y = fmaxf(bfhi(v.z)*ga + be, 0.f);
    r1.z = fmaxf(bflo(v.w)*ga + be, 0.f);
    r1.w = fmaxf(bfhi(v.w)*ga + be, 0.f);
    *(float4*)(out + idx)     = r0;
    *(float4*)(out + idx + 4) = r1;
}

extern "C" void kernel_launch(void* const* d_in, const int* in_sizes, int n_in,
                              void* d_out, int out_size, void* d_ws, size_t ws_size,
                              hipStream_t stream) {
    const float* f        = (const float*)d_in[0];
    const float* w_off    = (const float*)d_in[1];
    const float* bn_gamma = (const float*)d_in[3];
    const float* bn_beta  = (const float*)d_in[4];
    const float* w_dsc    = (const float*)d_in[5];
    const float* b_dsc    = (const float*)d_in[6];
    const float* gn_gamma = (const float*)d_in[7];
    const float* gn_beta  = (const float*)d_in[8];

    float* ws      = (float*)d_ws;
    unsigned short* featbf = (unsigned short*)(ws + FEATBF_OFF);
    unsigned short* xprebf = (unsigned short*)(ws + XPRE_OFF);
    float* off_pre = ws + OFFPRE_OFF;
    float* off_half= ws + OFFH_OFF;
    unsigned short* wTbf = (unsigned short*)(ws + WT_OFF);
    float* wP      = ws + WP_OFF;
    float* bnstats = ws + BNSTATS_OFF;
    float* gstats  = ws + GSTATS_OFF;

    hipMemsetAsync(bnstats, 0, STATS_BYTES, stream);

    k_nhwc<<<2048, 256, 0, stream>>>(f, featbf);
    k_wprep<<<165, 256, 0, stream>>>(w_dsc, wTbf, w_off, wP);
    k_conv_off<<<4096, 128, 0, stream>>>(f, wP, off_half);
    k_bn_stats<<<288, 256, 0, stream>>>(off_half, off_pre, bnstats);
    k_sample_dsc<<<2048, 256, 0, stream>>>(featbf, off_pre, bnstats, bn_gamma, bn_beta,
                                           wTbf, b_dsc, xprebf, gstats);
    k_gn_apply<<<4096, 256, 0, stream>>>(xprebf, gstats, gn_gamma, gn_beta, (float*)d_out);
}